// Round 1
// baseline (268.847 us; speedup 1.0000x reference)
//
#include <hip/hip_runtime.h>

#define SEQ   2048
#define DIM   64
#define NB    2
#define NH    16
#define BQ    64
#define BK    64
#define PADK  68
#define NKT   (SEQ / BK)

typedef float f32x4  __attribute__((ext_vector_type(4)));
typedef short bf16x8 __attribute__((ext_vector_type(8)));
typedef short s16x4  __attribute__((ext_vector_type(4)));

__device__ __forceinline__ short f2bf(float x) {
    unsigned u = __float_as_uint(x);
    return (short)((u + 0x7FFFu + ((u >> 16) & 1u)) >> 16);
}

// Load one 16x32 MFMA operand fragment (assumed split-4 k-mapping) from a
// row-major LDS tile row. Same mapping used for A and B of every MFMA, so a
// k-permutation mismatch vs hardware cancels out.
__device__ __forceinline__ bf16x8 ldfrag(const short* rowptr, int kbase) {
    s16x4 lo = *reinterpret_cast<const s16x4*>(rowptr + kbase);
    s16x4 hi = *reinterpret_cast<const s16x4*>(rowptr + kbase + 16);
    bf16x8 f;
    f[0] = lo[0]; f[1] = lo[1]; f[2] = lo[2]; f[3] = lo[3];
    f[4] = hi[0]; f[5] = hi[1]; f[6] = hi[2]; f[7] = hi[3];
    return f;
}

__global__ __launch_bounds__(256, 4)
void sdpa_fused_kernel(const float* __restrict__ Qp, const float* __restrict__ Kp,
                       const float* __restrict__ Vp, const int* __restrict__ Mp,
                       float* __restrict__ Op, float* __restrict__ Pp)
{
    __shared__ short Qs[BQ][PADK];
    __shared__ short Ks[BK][PADK];
    __shared__ short Vt[DIM][PADK];   // V transposed: [d][key]
    __shared__ short Ps[BQ][PADK];

    const int tid  = (int)threadIdx.x;
    const int lane = tid & 63;
    const int w    = tid >> 6;            // wave 0..3, owns q-rows w*16..w*16+15
    const int mrow = lane & 15;           // M/N index within 16
    const int kgrp = (lane >> 4) << 2;    // k-group base: 0,4,8,12

    const int qt = (int)blockIdx.x;
    const int bh = (int)blockIdx.y;

    const size_t headoff = (size_t)bh * SEQ * DIM;
    const float* Qg = Qp + headoff + (size_t)qt * BQ * DIM;
    const float* Kg = Kp + headoff;
    const float* Vg = Vp + headoff;
    const int*   Mg = Mp + (size_t)(bh / NH) * SEQ;
    float*       Og = Op + headoff + (size_t)qt * BQ * DIM;
    float*       Pg = Pp + ((size_t)bh * SEQ + (size_t)qt * BQ) * SEQ;

    const int r0 = tid >> 4;
    const int c0 = (tid & 15) << 2;

    // ---- stage Q tile (f32 -> bf16 LDS) ----
    #pragma unroll
    for (int i = 0; i < 4; ++i) {
        const int row = r0 + (i << 4);
        const float4 v = *reinterpret_cast<const float4*>(Qg + row * DIM + c0);
        s16x4 s;
        s[0] = f2bf(v.x); s[1] = f2bf(v.y); s[2] = f2bf(v.z); s[3] = f2bf(v.w);
        *reinterpret_cast<s16x4*>(&Qs[row][c0]) = s;
    }
    __syncthreads();

    const bf16x8 qf0 = ldfrag(&Qs[w * 16 + mrow][0], kgrp);
    const bf16x8 qf1 = ldfrag(&Qs[w * 16 + mrow][0], 32 + kgrp);

    // ================= pass 1: l[row] = sum_k exp(s) over unmasked =================
    float lsum[4] = {0.f, 0.f, 0.f, 0.f};

    for (int kt = 0; kt < NKT; ++kt) {
        __syncthreads();
        {
            const float* src = Kg + (size_t)kt * BK * DIM;
            #pragma unroll
            for (int i = 0; i < 4; ++i) {
                const int row = r0 + (i << 4);
                const float4 v = *reinterpret_cast<const float4*>(src + row * DIM + c0);
                s16x4 s;
                s[0] = f2bf(v.x); s[1] = f2bf(v.y); s[2] = f2bf(v.z); s[3] = f2bf(v.w);
                *reinterpret_cast<s16x4*>(&Ks[row][c0]) = s;
            }
        }
        __syncthreads();

        const int k0 = kt * BK;
        #pragma unroll
        for (int t = 0; t < 4; ++t) {
            const bf16x8 kf0 = ldfrag(&Ks[t * 16 + mrow][0], kgrp);
            const bf16x8 kf1 = ldfrag(&Ks[t * 16 + mrow][0], 32 + kgrp);
            f32x4 acc = {0.f, 0.f, 0.f, 0.f};
            acc = __builtin_amdgcn_mfma_f32_16x16x32_bf16(qf0, kf0, acc, 0, 0, 0);
            acc = __builtin_amdgcn_mfma_f32_16x16x32_bf16(qf1, kf1, acc, 0, 0, 0);
            const float mz = Mg[k0 + t * 16 + mrow] ? 0.f : 1.f;
            #pragma unroll
            for (int r = 0; r < 4; ++r)
                lsum[r] += mz * __expf(acc[r] * 0.125f);
        }
    }

    float rinv[4];
    #pragma unroll
    for (int r = 0; r < 4; ++r) {
        float v = lsum[r];
        v += __shfl_xor(v, 1);
        v += __shfl_xor(v, 2);
        v += __shfl_xor(v, 4);
        v += __shfl_xor(v, 8);
        rinv[r] = 1.0f / v;
    }

    // ================= pass 2: P = exp(s)/l  (write) ; O += P V =================
    f32x4 oacc[4];
    #pragma unroll
    for (int n = 0; n < 4; ++n) {
        oacc[n][0] = 0.f; oacc[n][1] = 0.f; oacc[n][2] = 0.f; oacc[n][3] = 0.f;
    }

    for (int kt = 0; kt < NKT; ++kt) {
        __syncthreads();
        {
            const float* src = Kg + (size_t)kt * BK * DIM;
            #pragma unroll
            for (int i = 0; i < 4; ++i) {
                const int row = r0 + (i << 4);
                const float4 v = *reinterpret_cast<const float4*>(src + row * DIM + c0);
                s16x4 s;
                s[0] = f2bf(v.x); s[1] = f2bf(v.y); s[2] = f2bf(v.z); s[3] = f2bf(v.w);
                *reinterpret_cast<s16x4*>(&Ks[row][c0]) = s;
            }
            const float* vsrc = Vg + (size_t)kt * BK * DIM;
            #pragma unroll
            for (int i = 0; i < 4; ++i) {
                const int key = r0 + (i << 4);
                const float4 v = *reinterpret_cast<const float4*>(vsrc + key * DIM + c0);
                Vt[c0 + 0][key] = f2bf(v.x);
                Vt[c0 + 1][key] = f2bf(v.y);
                Vt[c0 + 2][key] = f2bf(v.z);
                Vt[c0 + 3][key] = f2bf(v.w);
            }
        }
        __syncthreads();

        const int k0 = kt * BK;
        #pragma unroll
        for (int t = 0; t < 4; ++t) {
            const bf16x8 kf0 = ldfrag(&Ks[t * 16 + mrow][0], kgrp);
            const bf16x8 kf1 = ldfrag(&Ks[t * 16 + mrow][0], 32 + kgrp);
            f32x4 acc = {0.f, 0.f, 0.f, 0.f};
            acc = __builtin_amdgcn_mfma_f32_16x16x32_bf16(qf0, kf0, acc, 0, 0, 0);
            acc = __builtin_amdgcn_mfma_f32_16x16x32_bf16(qf1, kf1, acc, 0, 0, 0);
            const int gkey = k0 + t * 16 + mrow;
            const float mz = Mg[gkey] ? 0.f : 1.f;
            #pragma unroll
            for (int r = 0; r < 4; ++r) {
                const float p = mz * __expf(acc[r] * 0.125f) * rinv[r];
                Ps[w * 16 + kgrp + r][t * 16 + mrow] = f2bf(p);
                Pg[(size_t)(w * 16 + kgrp + r) * SEQ + gkey] = p;
            }
        }

        // P rows for this wave are written only by this wave -> no barrier needed.
        const bf16x8 pf0 = ldfrag(&Ps[w * 16 + mrow][0], kgrp);
        const bf16x8 pf1 = ldfrag(&Ps[w * 16 + mrow][0], 32 + kgrp);
        #pragma unroll
        for (int n = 0; n < 4; ++n) {
            const bf16x8 vf0 = ldfrag(&Vt[n * 16 + mrow][0], kgrp);
            const bf16x8 vf1 = ldfrag(&Vt[n * 16 + mrow][0], 32 + kgrp);
            oacc[n] = __builtin_amdgcn_mfma_f32_16x16x32_bf16(pf0, vf0, oacc[n], 0, 0, 0);
            oacc[n] = __builtin_amdgcn_mfma_f32_16x16x32_bf16(pf1, vf1, oacc[n], 0, 0, 0);
        }
    }

    #pragma unroll
    for (int n = 0; n < 4; ++n) {
        #pragma unroll
        for (int r = 0; r < 4; ++r)
            Og[(size_t)(w * 16 + kgrp + r) * DIM + n * 16 + mrow] = oacc[n][r];
    }
}

extern "C" void kernel_launch(void* const* d_in, const int* in_sizes, int n_in,
                              void* d_out, int out_size, void* d_ws, size_t ws_size,
                              hipStream_t stream) {
    const float* Q = (const float*)d_in[0];
    const float* K = (const float*)d_in[1];
    const float* V = (const float*)d_in[2];
    const int*   M = (const int*)d_in[3];
    float* O = (float*)d_out;
    float* P = O + (size_t)NB * NH * SEQ * DIM;   // weights follow output

    dim3 grid(SEQ / BQ, NB * NH);
    sdpa_fused_kernel<<<grid, dim3(256, 1, 1), 0, stream>>>(Q, K, V, M, O, P);
}